// Round 6
// baseline (3691.650 us; speedup 1.0000x reference)
//
#include <hip/hip_runtime.h>
#include <hip/hip_bf16.h>
#include <cstdint>

// Problem constants
#define B_   64
#define T_   512
#define IN_  512
#define H_   1024
#define O_   512
#define NG   4096              // 4*H, gate-interleaved: n = 4h+g
#define KC   1536              // IN_ + H_
#define BT   32768             // B*T
#define BH   65536             // ushorts per h slot (B*H)
#define NWG  256               // one WG per CU

using bs8 = __attribute__((ext_vector_type(8))) short;   // 8 x bf16
using f4  = __attribute__((ext_vector_type(4))) float;

__device__ __forceinline__ ushort f2bf(float f) {
    union { float f; uint32_t u; } v; v.f = f;
    uint32_t r = v.u + 0x7fffu + ((v.u >> 16) & 1u);
    return (ushort)(r >> 16);
}
__device__ __forceinline__ float sigm(float x) { return 1.f / (1.f + __expf(-x)); }
__device__ __forceinline__ float tanh_(float x) {
    x = fminf(fmaxf(x, -15.f), 15.f);
    float e = __expf(2.f * x);
    return (e - 1.f) / (e + 1.f);
}

// ---------------- conversion / layout kernels ----------------

// xP[t][kk][b][32] (kk = k/32, 16 chunks of IN_), coalesced consumer reads
__global__ void k_pack_x(const float* __restrict__ x, ushort* __restrict__ xP) {
    const int n8 = BT * IN_ / 8;
    for (int i = blockIdx.x * blockDim.x + threadIdx.x; i < n8; i += gridDim.x * blockDim.x) {
        const int e8 = i & 3, b = (i >> 2) & 63, kk = (i >> 8) & 15, t = i >> 12;
        const float* s = x + ((size_t)b * T_ + t) * IN_ + kk * 32 + e8 * 8;
        f4 v0 = *reinterpret_cast<const f4*>(s);
        f4 v1 = *reinterpret_cast<const f4*>(s + 4);
        uint4 q;
        q.x = (uint32_t)f2bf(v0[0]) | ((uint32_t)f2bf(v0[1]) << 16);
        q.y = (uint32_t)f2bf(v0[2]) | ((uint32_t)f2bf(v0[3]) << 16);
        q.z = (uint32_t)f2bf(v1[0]) | ((uint32_t)f2bf(v1[1]) << 16);
        q.w = (uint32_t)f2bf(v1[2]) | ((uint32_t)f2bf(v1[3]) << 16);
        *reinterpret_cast<uint4*>(xP + ((size_t)t * 16 + kk) * 2048 + b * 32 + e8 * 8) = q;
    }
}

// WcT[n][k] (bf16), n = 4h+g; k<512 -> Wx_g[k][h], k>=512 -> Wh_g[k-512][h]
__global__ void k_build_wcT(const float* __restrict__ xi, const float* __restrict__ xf,
                            const float* __restrict__ xo, const float* __restrict__ xc,
                            const float* __restrict__ hi, const float* __restrict__ hf,
                            const float* __restrict__ ho, const float* __restrict__ hc,
                            ushort* __restrict__ dst) {
    const int total = NG * KC;
    for (int i = blockIdx.x * blockDim.x + threadIdx.x; i < total; i += gridDim.x * blockDim.x) {
        int n = i / KC, k = i - n * KC;
        int g = n & 3, h = n >> 2;
        float v;
        if (k < IN_) {
            const float* s = (g == 0) ? xi : ((g == 1) ? xf : ((g == 2) ? xo : xc));
            v = s[(size_t)k * H_ + h];
        } else {
            const float* s = (g == 0) ? hi : ((g == 1) ? hf : ((g == 2) ? ho : hc));
            v = s[(size_t)(k - IN_) * H_ + h];
        }
        dst[i] = f2bf(v);
    }
}

__global__ void k_build_whyT(const float* __restrict__ w, ushort* __restrict__ dst) {
    const int total = O_ * H_;
    for (int i = blockIdx.x * blockDim.x + threadIdx.x; i < total; i += gridDim.x * blockDim.x) {
        int o = i >> 10, k = i & (H_ - 1);
        dst[i] = f2bf(w[(size_t)k * O_ + o]);
    }
}

__global__ void k_build_bias(const float* __restrict__ bi, const float* __restrict__ bff,
                             const float* __restrict__ bo, const float* __restrict__ bc,
                             float* __restrict__ dst) {
    int i = blockIdx.x * blockDim.x + threadIdx.x;
    if (i < NG) {
        int g = i & 3, h = i >> 2;
        dst[i] = (g == 0) ? bi[h] : ((g == 1) ? bff[h] : ((g == 2) ? bo[h] : bc[h]));
    }
}

// ---------------- persistent LSTM, W in registers ----------------
// WG g (1/CU): gate rows n0=g*16 (4 h-units). 4 waves split K 4-way interleaved:
// wave w owns K-chunks c = w+4j (j=0..11; c<16 -> x, else h). A-fragments (12 bs8)
// live in VGPRs for the whole kernel. Partials reduced via LDS (16 KB).
__global__ void __launch_bounds__(256, 1)
k_persist(const ushort* __restrict__ WcT, const ushort* __restrict__ xP,
          ushort* __restrict__ hs, float* __restrict__ cst,
          const float* __restrict__ biasc, uint32_t* __restrict__ flags,
          int t0, int nsteps) {
    __shared__ f4 part[4][4][64];     // [src wave][b-tile][lane], 16 KB
    __shared__ ushort hout[64][4];    // 512 B
    const int g = blockIdx.x, tid = threadIdx.x;
    const int lane = tid & 63, w = tid >> 6;
    const int n0 = g * 16;
    const int l15 = lane & 15, lq = lane >> 4;

    // stage W fragments into registers (A-frag: row = n0+l15, k = c*32 + lq*8 + j)
    bs8 wf[12];
#pragma unroll
    for (int j = 0; j < 12; ++j) {
        const int c = w + 4 * j;
        wf[j] = *reinterpret_cast<const bs8*>(WcT + (size_t)(n0 + l15) * KC + c * 32 + lq * 8);
    }

    // this thread's elementwise cell: b = w*16 + l15, h-unit u = g*4 + lq
    const int bmy = w * 16 + l15;
    const int u = g * 4 + lq;
    const f4 bia = *reinterpret_cast<const f4*>(biasc + n0 + lq * 4);
    float creg = (t0 == 0) ? 0.f : cst[(size_t)bmy * H_ + u];

    // B-operand lane base: within chunk, offset = (bt*16+l15)*32 + lq*8
    const ushort* xb = xP + (size_t)l15 * 32 + lq * 8;
    const ushort* hb = hs + (size_t)l15 * 32 + lq * 8;

    // prefetch x for step 0
    bs8 xv[16];
#pragma unroll
    for (int j = 0; j < 4; ++j)
#pragma unroll
        for (int bt = 0; bt < 4; ++bt)
            xv[j * 4 + bt] = *reinterpret_cast<const bs8*>(
                xb + ((size_t)t0 * 16 + (w + 4 * j)) * 2048 + bt * 512);

    for (int s = 0; s < nsteps; ++s) {
        // 1) issue all 32 h loads first (MLP; h_s visible per previous poll)
        const ushort* hsl = hb + (size_t)s * BH;
        bs8 hv[32];
#pragma unroll
        for (int j = 0; j < 8; ++j)
#pragma unroll
            for (int bt = 0; bt < 4; ++bt)
                hv[j * 4 + bt] = *reinterpret_cast<const bs8*>(
                    hsl + (size_t)(w + 4 * j) * 2048 + bt * 512);

        // 2) x MFMAs (operands already in regs) overlap the h-load latency
        f4 acc[4] = {{0.f,0.f,0.f,0.f},{0.f,0.f,0.f,0.f},{0.f,0.f,0.f,0.f},{0.f,0.f,0.f,0.f}};
#pragma unroll
        for (int j = 0; j < 4; ++j)
#pragma unroll
            for (int bt = 0; bt < 4; ++bt)
                acc[bt] = __builtin_amdgcn_mfma_f32_16x16x32_bf16(wf[j], xv[j * 4 + bt], acc[bt], 0, 0, 0);

        // 3) h MFMAs
#pragma unroll
        for (int j = 0; j < 8; ++j)
#pragma unroll
            for (int bt = 0; bt < 4; ++bt)
                acc[bt] = __builtin_amdgcn_mfma_f32_16x16x32_bf16(wf[4 + j], hv[j * 4 + bt], acc[bt], 0, 0, 0);

        // 4) K-split reduce via LDS
#pragma unroll
        for (int bt = 0; bt < 4; ++bt) part[w][bt][lane] = acc[bt];
        __syncthreads();

        f4 ssum = part[0][w][lane] + part[1][w][lane] + part[2][w][lane] + part[3][w][lane];
        float pi = ssum[0] + bia[0], pf = ssum[1] + bia[1];
        float po = ssum[2] + bia[2], pc = ssum[3] + bia[3];
        float iv = sigm(pi), fv = sigm(pf), ov = sigm(po), cv = tanh_(pc);
        creg = fv * creg + iv * cv;
        hout[bmy][lq] = f2bf(ov * tanh_(creg));
        __syncthreads();

        // 5) wave 0: coherent 8B/lane store of this WG's h slice; release flag
        if (w == 0) {
            uint2 hv2 = *reinterpret_cast<uint2*>(&hout[lane][0]);
            ushort* dst = hs + (size_t)(s + 1) * BH + (size_t)(g >> 3) * 2048
                        + (size_t)lane * 32 + (g & 7) * 4;
            asm volatile("global_store_dwordx2 %0, %1, off sc0 sc1" :: "v"(dst), "v"(hv2) : "memory");
            asm volatile("s_waitcnt vmcnt(0)" ::: "memory");
            if (tid == 0)
                __hip_atomic_store(&flags[g], (uint32_t)(s + 1),
                                   __ATOMIC_RELAXED, __HIP_MEMORY_SCOPE_AGENT);
        }

        if (s + 1 < nsteps) {
            // prefetch next x during the wait window
#pragma unroll
            for (int j = 0; j < 4; ++j)
#pragma unroll
                for (int bt = 0; bt < 4; ++bt)
                    xv[j * 4 + bt] = *reinterpret_cast<const bs8*>(
                        xb + ((size_t)(t0 + s + 1) * 16 + (w + 4 * j)) * 2048 + bt * 512);
            // wave 0 polls all 256 flags (4 per lane)
            if (w == 0) {
                const uint32_t tgt = (uint32_t)(s + 1);
                for (;;) {
                    uint32_t f0 = __hip_atomic_load(&flags[lane],       __ATOMIC_RELAXED, __HIP_MEMORY_SCOPE_AGENT);
                    uint32_t f1 = __hip_atomic_load(&flags[64 + lane],  __ATOMIC_RELAXED, __HIP_MEMORY_SCOPE_AGENT);
                    uint32_t f2 = __hip_atomic_load(&flags[128 + lane], __ATOMIC_RELAXED, __HIP_MEMORY_SCOPE_AGENT);
                    uint32_t f3 = __hip_atomic_load(&flags[192 + lane], __ATOMIC_RELAXED, __HIP_MEMORY_SCOPE_AGENT);
                    if (__all((int)(f0 >= tgt && f1 >= tgt && f2 >= tgt && f3 >= tgt))) break;
                    __builtin_amdgcn_s_sleep(1);
                }
            }
            __syncthreads();   // release all waves; h_{s+1} visible
        }
    }

    cst[(size_t)bmy * H_ + u] = creg;
}

// ---------------- output projection (packed h input) ----------------
__global__ void __launch_bounds__(64) k_yproj(const ushort* __restrict__ WhyT,
                                              const ushort* __restrict__ hsbase,
                                              const float* __restrict__ by,
                                              float* __restrict__ out, int t_off) {
    const int lane = threadIdx.x;
    const int tloc = blockIdx.x;
    const int o0 = blockIdx.y * 64;
    const int l15 = lane & 15, lq = lane >> 4, lk = lq * 8;
    const int t = t_off + tloc;

    const ushort* slot = hsbase + (size_t)(tloc + 1) * BH;
    const ushort* apm[4]; const ushort* bp[4];
#pragma unroll
    for (int m = 0; m < 4; ++m) apm[m] = WhyT + (size_t)(o0 + m * 16 + l15) * H_ + lk;
#pragma unroll
    for (int n = 0; n < 4; ++n) bp[n] = slot + (size_t)(n * 16 + l15) * 32 + lk;

    f4 acc[4][4] = {};
    for (int kk = 0; kk < 32; ++kk) {
        bs8 a[4], b[4];
#pragma unroll
        for (int m = 0; m < 4; ++m) a[m] = *reinterpret_cast<const bs8*>(apm[m] + kk * 32);
#pragma unroll
        for (int n = 0; n < 4; ++n) b[n] = *reinterpret_cast<const bs8*>(bp[n] + (size_t)kk * 2048);
#pragma unroll
        for (int m = 0; m < 4; ++m)
#pragma unroll
            for (int n = 0; n < 4; ++n)
                acc[m][n] = __builtin_amdgcn_mfma_f32_16x16x32_bf16(a[m], b[n], acc[m][n], 0, 0, 0);
    }

#pragma unroll
    for (int m = 0; m < 4; ++m) {
        const int ob = o0 + m * 16 + lq * 4;
        const f4 bb = *reinterpret_cast<const f4*>(by + ob);
#pragma unroll
        for (int n = 0; n < 4; ++n) {
            const int b_ = n * 16 + l15;
            f4 v = acc[m][n] + bb;
            *reinterpret_cast<f4*>(out + ((size_t)b_ * T_ + t) * O_ + ob) = v;
        }
    }
}

// ---------------- launch ----------------

extern "C" void kernel_launch(void* const* d_in, const int* in_sizes, int n_in,
                              void* d_out, int out_size, void* d_ws, size_t ws_size,
                              hipStream_t stream) {
    const float* x   = (const float*)d_in[0];
    const float* wxi = (const float*)d_in[1];
    const float* whi = (const float*)d_in[2];
    const float* bi  = (const float*)d_in[3];
    const float* wxf = (const float*)d_in[4];
    const float* whf = (const float*)d_in[5];
    const float* bf_ = (const float*)d_in[6];
    const float* wxo = (const float*)d_in[7];
    const float* who = (const float*)d_in[8];
    const float* bo  = (const float*)d_in[9];
    const float* wxc = (const float*)d_in[10];
    const float* whc = (const float*)d_in[11];
    const float* bc  = (const float*)d_in[12];
    const float* why = (const float*)d_in[13];
    const float* by  = (const float*)d_in[14];
    float* out = (float*)d_out;

    uint8_t* w = (uint8_t*)d_ws;
    ushort*   xP    = (ushort*)  (w);                  // 33,554,432
    ushort*   WcT   = (ushort*)  (w + 33554432);       // 12,582,912
    ushort*   WhyT  = (ushort*)  (w + 46137344);       //  1,048,576
    float*    biasc = (float*)   (w + 47185920);       //     16,384
    float*    cst   = (float*)   (w + 47202304);       //    262,144
    uint32_t* flags = (uint32_t*)(w + 47464448);       //      4,096 (256 used)
    ushort*   hs    = (ushort*)  (w + 47468544);
    const size_t NEED_A = 47468544 + (size_t)(T_ + 1) * BH * 2;  // 114,708,480
    const size_t NEED_B = 47468544 + (size_t)65 * BH * 2;        //  55,988,224
    if (ws_size < NEED_B) return;
    const bool fullhs = (ws_size >= NEED_A);

    k_pack_x<<<2048, 256, 0, stream>>>(x, xP);
    k_build_wcT<<<4096, 256, 0, stream>>>(wxi, wxf, wxo, wxc, whi, whf, who, whc, WcT);
    k_build_whyT<<<512, 256, 0, stream>>>(why, WhyT);
    k_build_bias<<<16, 256, 0, stream>>>(bi, bf_, bo, bc, biasc);

    hipMemsetAsync(cst, 0, (size_t)BH * 4, stream);
    hipMemsetAsync(hs,  0, (size_t)BH * 2, stream);

    const int nchunk = fullhs ? 1 : 8;
    const int steps  = fullhs ? T_ : 64;
    for (int c = 0; c < nchunk; ++c) {
        const int t0 = c * steps;
        hipMemsetAsync(flags, 0, NWG * 4, stream);
        const ushort* a0 = WcT; const ushort* a1 = xP; ushort* a2 = hs;
        float* a3 = cst; const float* a4 = biasc; uint32_t* a5 = flags;
        int a6 = t0, a7 = steps;
        void* args[8] = {&a0, &a1, &a2, &a3, &a4, &a5, &a6, &a7};
        hipError_t e = hipLaunchCooperativeKernel((const void*)k_persist,
                                                  dim3(NWG), dim3(256), args, 0, stream);
        if (e != hipSuccess) {
            // fallback: plain launch; 256 single-WG/CU blocks are co-resident
            k_persist<<<dim3(NWG), dim3(256), 0, stream>>>(WcT, xP, hs, cst, biasc,
                                                           flags, t0, steps);
        }
        if (!fullhs) {
            k_yproj<<<dim3(64, O_ / 64), 64, 0, stream>>>(WhyT, hs, by, out, t0);
            if (c != nchunk - 1)
                hipMemcpyAsync(hs, hs + (size_t)64 * BH, (size_t)BH * 2,
                               hipMemcpyDeviceToDevice, stream);
        }
    }
    if (fullhs)
        k_yproj<<<dim3(T_, O_ / 64), 64, 0, stream>>>(WhyT, hs, by, out, 0);
}

// Round 7
// 3288.334 us; speedup vs baseline: 1.1227x; 1.1227x over previous
//
#include <hip/hip_runtime.h>
#include <hip/hip_bf16.h>
#include <cstdint>

// Problem constants
#define B_   64
#define T_   512
#define IN_  512
#define H_   1024
#define O_   512
#define NG   4096              // 4*H, gate-interleaved: n = 4h+g
#define KC   1536              // IN_ + H_
#define BT   32768             // B*T
#define BH   65536             // ushorts per h slot (B*H)
#define NWG  256               // one WG per CU

#define GLB __attribute__((address_space(1)))
#define LDSAS __attribute__((address_space(3)))

using bs8 = __attribute__((ext_vector_type(8))) short;   // 8 x bf16
using f4  = __attribute__((ext_vector_type(4))) float;

__device__ __forceinline__ ushort f2bf(float f) {
    union { float f; uint32_t u; } v; v.f = f;
    uint32_t r = v.u + 0x7fffu + ((v.u >> 16) & 1u);
    return (ushort)(r >> 16);
}
__device__ __forceinline__ float sigm(float x) { return 1.f / (1.f + __expf(-x)); }
__device__ __forceinline__ float tanh_(float x) {
    x = fminf(fmaxf(x, -15.f), 15.f);
    float e = __expf(2.f * x);
    return (e - 1.f) / (e + 1.f);
}

// ---------------- conversion / layout kernels ----------------

// xP[t][kk][b][32] (kk = k/32, 16 chunks of IN_), coalesced consumer reads
__global__ void k_pack_x(const float* __restrict__ x, ushort* __restrict__ xP) {
    const int n8 = BT * IN_ / 8;
    for (int i = blockIdx.x * blockDim.x + threadIdx.x; i < n8; i += gridDim.x * blockDim.x) {
        const int e8 = i & 3, b = (i >> 2) & 63, kk = (i >> 8) & 15, t = i >> 12;
        const float* s = x + ((size_t)b * T_ + t) * IN_ + kk * 32 + e8 * 8;
        f4 v0 = *reinterpret_cast<const f4*>(s);
        f4 v1 = *reinterpret_cast<const f4*>(s + 4);
        uint4 q;
        q.x = (uint32_t)f2bf(v0[0]) | ((uint32_t)f2bf(v0[1]) << 16);
        q.y = (uint32_t)f2bf(v0[2]) | ((uint32_t)f2bf(v0[3]) << 16);
        q.z = (uint32_t)f2bf(v1[0]) | ((uint32_t)f2bf(v1[1]) << 16);
        q.w = (uint32_t)f2bf(v1[2]) | ((uint32_t)f2bf(v1[3]) << 16);
        *reinterpret_cast<uint4*>(xP + ((size_t)t * 16 + kk) * 2048 + b * 32 + e8 * 8) = q;
    }
}

// WcT[n][k] (bf16), n = 4h+g; k<512 -> Wx_g[k][h], k>=512 -> Wh_g[k-512][h]
__global__ void k_build_wcT(const float* __restrict__ xi, const float* __restrict__ xf,
                            const float* __restrict__ xo, const float* __restrict__ xc,
                            const float* __restrict__ hi, const float* __restrict__ hf,
                            const float* __restrict__ ho, const float* __restrict__ hc,
                            ushort* __restrict__ dst) {
    const int total = NG * KC;
    for (int i = blockIdx.x * blockDim.x + threadIdx.x; i < total; i += gridDim.x * blockDim.x) {
        int n = i / KC, k = i - n * KC;
        int g = n & 3, h = n >> 2;
        float v;
        if (k < IN_) {
            const float* s = (g == 0) ? xi : ((g == 1) ? xf : ((g == 2) ? xo : xc));
            v = s[(size_t)k * H_ + h];
        } else {
            const float* s = (g == 0) ? hi : ((g == 1) ? hf : ((g == 2) ? ho : hc));
            v = s[(size_t)(k - IN_) * H_ + h];
        }
        dst[i] = f2bf(v);
    }
}

__global__ void k_build_whyT(const float* __restrict__ w, ushort* __restrict__ dst) {
    const int total = O_ * H_;
    for (int i = blockIdx.x * blockDim.x + threadIdx.x; i < total; i += gridDim.x * blockDim.x) {
        int o = i >> 10, k = i & (H_ - 1);
        dst[i] = f2bf(w[(size_t)k * O_ + o]);
    }
}

__global__ void k_build_bias(const float* __restrict__ bi, const float* __restrict__ bff,
                             const float* __restrict__ bo, const float* __restrict__ bc,
                             float* __restrict__ dst) {
    int i = blockIdx.x * blockDim.x + threadIdx.x;
    if (i < NG) {
        int g = i & 3, h = i >> 2;
        dst[i] = (g == 0) ? bi[h] : ((g == 1) ? bff[h] : ((g == 2) ? bo[h] : bc[h]));
    }
}

// ---------------- persistent LSTM: W in registers, h via global_load_lds ----------------
// WG g (1/CU): gate rows n0=g*16 (4 h-units). wf[48] = full W slice in VGPRs.
// 4 waves, wave w = b-tile w (16 batches, full K). No K-split reduce.
// Per step: stage h slot -> LDS (32 gll/wave, async) || x-MFMAs; vmcnt0+bar;
// 32 ds_read_b128+MFMA; elementwise (c in regs); hout repack; sc0sc1 store; flag barrier.
__global__ void __launch_bounds__(256, 1)
k_persist(const ushort* __restrict__ WcT, const ushort* __restrict__ xP,
          ushort* __restrict__ hs, float* __restrict__ cst,
          const float* __restrict__ biasc, uint32_t* __restrict__ flags,
          int t0, int nsteps) {
    __shared__ ushort Hst[32 * 2048];     // 128 KB: staged h slot, [kk][b][32] linear
    __shared__ ushort hout[64][4];        // 512 B
    const int g = blockIdx.x, tid = threadIdx.x;
    const int lane = tid & 63, w = tid >> 6;
    const int n0 = g * 16;
    const int l15 = lane & 15, lq = lane >> 4;

    // W slice -> registers: chunk c (32 k), lane holds row n0+l15, k = c*32 + lq*8 ..+8
    bs8 wf[48];
#pragma unroll
    for (int c = 0; c < 48; ++c)
        wf[c] = *reinterpret_cast<const bs8*>(WcT + (size_t)(n0 + l15) * KC + c * 32 + lq * 8);

    // this thread's elementwise cell: b = w*16+l15, h-unit u = g*4+lq
    const int bmy = w * 16 + l15;
    const int u = g * 4 + lq;
    const f4 bia = *reinterpret_cast<const f4*>(biasc + n0 + lq * 4);
    float creg = (t0 == 0) ? 0.f : cst[(size_t)bmy * H_ + u];

    // B-operand base for this wave's b-tile (byte-contiguous 1KB per chunk per wave)
    const ushort* xb = xP + (size_t)bmy * 32 + lq * 8;

    // prefetch x chunks for step 0
    bs8 xv[16];
#pragma unroll
    for (int c = 0; c < 16; ++c)
        xv[c] = *reinterpret_cast<const bs8*>(xb + ((size_t)t0 * 16 + c) * 2048);

    __syncthreads();

    for (int s = 0; s < nsteps; ++s) {
        // 1) async-stage h_s (visible per previous poll) into LDS: wave w -> chunks 8w..8w+7
        const ushort* hslot = hs + (size_t)s * BH;
#pragma unroll
        for (int j = 0; j < 8; ++j) {
            const int c = w * 8 + j;
            const ushort* gp = hslot + (size_t)c * 2048 + (size_t)lane * 8;
            ushort* lp = &Hst[c * 2048];
#pragma unroll
            for (int i = 0; i < 4; ++i)
                __builtin_amdgcn_global_load_lds((const GLB uint32_t*)(gp + i * 512),
                                                 (LDSAS uint32_t*)(lp + i * 512), 16, 0, 0);
        }

        // 2) x-MFMAs (reg operands) overlap the staging; 4 partial accs for ILP
        f4 a0 = {0.f,0.f,0.f,0.f}, a1 = {0.f,0.f,0.f,0.f};
        f4 a2 = {0.f,0.f,0.f,0.f}, a3 = {0.f,0.f,0.f,0.f};
#pragma unroll
        for (int c = 0; c < 16; c += 4) {
            a0 = __builtin_amdgcn_mfma_f32_16x16x32_bf16(wf[c + 0], xv[c + 0], a0, 0, 0, 0);
            a1 = __builtin_amdgcn_mfma_f32_16x16x32_bf16(wf[c + 1], xv[c + 1], a1, 0, 0, 0);
            a2 = __builtin_amdgcn_mfma_f32_16x16x32_bf16(wf[c + 2], xv[c + 2], a2, 0, 0, 0);
            a3 = __builtin_amdgcn_mfma_f32_16x16x32_bf16(wf[c + 3], xv[c + 3], a3, 0, 0, 0);
        }

        asm volatile("s_waitcnt vmcnt(0)" ::: "memory");
        __syncthreads();   // all waves' staged chunks visible

        // 3) h-MFMAs: 32 chunks from LDS (contiguous 1KB per wave -> conflict-free)
        const char* hstb = (const char*)&Hst[0] + (size_t)bmy * 64 + lq * 16;
#pragma unroll
        for (int c = 0; c < 32; c += 4) {
            bs8 h0 = *reinterpret_cast<const bs8*>(hstb + (size_t)(c + 0) * 4096);
            bs8 h1 = *reinterpret_cast<const bs8*>(hstb + (size_t)(c + 1) * 4096);
            bs8 h2 = *reinterpret_cast<const bs8*>(hstb + (size_t)(c + 2) * 4096);
            bs8 h3 = *reinterpret_cast<const bs8*>(hstb + (size_t)(c + 3) * 4096);
            a0 = __builtin_amdgcn_mfma_f32_16x16x32_bf16(wf[16 + c + 0], h0, a0, 0, 0, 0);
            a1 = __builtin_amdgcn_mfma_f32_16x16x32_bf16(wf[16 + c + 1], h1, a1, 0, 0, 0);
            a2 = __builtin_amdgcn_mfma_f32_16x16x32_bf16(wf[16 + c + 2], h2, a2, 0, 0, 0);
            a3 = __builtin_amdgcn_mfma_f32_16x16x32_bf16(wf[16 + c + 3], h3, a3, 0, 0, 0);
        }
        f4 ssum = (a0 + a1) + (a2 + a3);

        // 4) elementwise; h -> LDS repack
        {
            float pi = ssum[0] + bia[0], pf = ssum[1] + bia[1];
            float po = ssum[2] + bia[2], pc = ssum[3] + bia[3];
            float iv = sigm(pi), fv = sigm(pf), ov = sigm(po), cv = tanh_(pc);
            creg = fv * creg + iv * cv;
            hout[bmy][lq] = f2bf(ov * tanh_(creg));
        }
        __syncthreads();

        // 5) wave 0: coherent 8B/lane store of this WG's h slice; release flag
        if (w == 0) {
            uint2 hv2 = *reinterpret_cast<uint2*>(&hout[lane][0]);
            ushort* dst = hs + (size_t)(s + 1) * BH + (size_t)(g >> 3) * 2048
                        + (size_t)lane * 32 + (g & 7) * 4;
            asm volatile("global_store_dwordx2 %0, %1, off sc0 sc1" :: "v"(dst), "v"(hv2) : "memory");
            asm volatile("s_waitcnt vmcnt(0)" ::: "memory");
            if (tid == 0)
                __hip_atomic_store(&flags[g], (uint32_t)(s + 1),
                                   __ATOMIC_RELAXED, __HIP_MEMORY_SCOPE_AGENT);
        }

        if (s + 1 < nsteps) {
            // prefetch next x during the wait window
#pragma unroll
            for (int c = 0; c < 16; ++c)
                xv[c] = *reinterpret_cast<const bs8*>(xb + ((size_t)(t0 + s + 1) * 16 + c) * 2048);
            // wave 0 polls all 256 flags (4 per lane)
            if (w == 0) {
                const uint32_t tgt = (uint32_t)(s + 1);
                for (;;) {
                    uint32_t f0 = __hip_atomic_load(&flags[lane],       __ATOMIC_RELAXED, __HIP_MEMORY_SCOPE_AGENT);
                    uint32_t f1 = __hip_atomic_load(&flags[64 + lane],  __ATOMIC_RELAXED, __HIP_MEMORY_SCOPE_AGENT);
                    uint32_t f2 = __hip_atomic_load(&flags[128 + lane], __ATOMIC_RELAXED, __HIP_MEMORY_SCOPE_AGENT);
                    uint32_t f3 = __hip_atomic_load(&flags[192 + lane], __ATOMIC_RELAXED, __HIP_MEMORY_SCOPE_AGENT);
                    if (__all((int)(f0 >= tgt && f1 >= tgt && f2 >= tgt && f3 >= tgt))) break;
                    __builtin_amdgcn_s_sleep(1);
                }
            }
            __syncthreads();   // release all waves; h_{s+1} visible, Hst free to overwrite
        }
    }

    cst[(size_t)bmy * H_ + u] = creg;
}

// ---------------- output projection (packed h input) ----------------
__global__ void __launch_bounds__(64) k_yproj(const ushort* __restrict__ WhyT,
                                              const ushort* __restrict__ hsbase,
                                              const float* __restrict__ by,
                                              float* __restrict__ out, int t_off) {
    const int lane = threadIdx.x;
    const int tloc = blockIdx.x;
    const int o0 = blockIdx.y * 64;
    const int l15 = lane & 15, lq = lane >> 4, lk = lq * 8;
    const int t = t_off + tloc;

    const ushort* slot = hsbase + (size_t)(tloc + 1) * BH;
    const ushort* apm[4]; const ushort* bp[4];
#pragma unroll
    for (int m = 0; m < 4; ++m) apm[m] = WhyT + (size_t)(o0 + m * 16 + l15) * H_ + lk;
#pragma unroll
    for (int n = 0; n < 4; ++n) bp[n] = slot + (size_t)(n * 16 + l15) * 32 + lk;

    f4 acc[4][4] = {};
    for (int kk = 0; kk < 32; ++kk) {
        bs8 a[4], b[4];
#pragma unroll
        for (int m = 0; m < 4; ++m) a[m] = *reinterpret_cast<const bs8*>(apm[m] + kk * 32);
#pragma unroll
        for (int n = 0; n < 4; ++n) b[n] = *reinterpret_cast<const bs8*>(bp[n] + (size_t)kk * 2048);
#pragma unroll
        for (int m = 0; m < 4; ++m)
#pragma unroll
            for (int n = 0; n < 4; ++n)
                acc[m][n] = __builtin_amdgcn_mfma_f32_16x16x32_bf16(a[m], b[n], acc[m][n], 0, 0, 0);
    }

#pragma unroll
    for (int m = 0; m < 4; ++m) {
        const int ob = o0 + m * 16 + lq * 4;
        const f4 bb = *reinterpret_cast<const f4*>(by + ob);
#pragma unroll
        for (int n = 0; n < 4; ++n) {
            const int b_ = n * 16 + l15;
            f4 v = acc[m][n] + bb;
            *reinterpret_cast<f4*>(out + ((size_t)b_ * T_ + t) * O_ + ob) = v;
        }
    }
}

// ---------------- launch ----------------

extern "C" void kernel_launch(void* const* d_in, const int* in_sizes, int n_in,
                              void* d_out, int out_size, void* d_ws, size_t ws_size,
                              hipStream_t stream) {
    const float* x   = (const float*)d_in[0];
    const float* wxi = (const float*)d_in[1];
    const float* whi = (const float*)d_in[2];
    const float* bi  = (const float*)d_in[3];
    const float* wxf = (const float*)d_in[4];
    const float* whf = (const float*)d_in[5];
    const float* bf_ = (const float*)d_in[6];
    const float* wxo = (const float*)d_in[7];
    const float* who = (const float*)d_in[8];
    const float* bo  = (const float*)d_in[9];
    const float* wxc = (const float*)d_in[10];
    const float* whc = (const float*)d_in[11];
    const float* bc  = (const float*)d_in[12];
    const float* why = (const float*)d_in[13];
    const float* by  = (const float*)d_in[14];
    float* out = (float*)d_out;

    uint8_t* w = (uint8_t*)d_ws;
    ushort*   xP    = (ushort*)  (w);                  // 33,554,432
    ushort*   WcT   = (ushort*)  (w + 33554432);       // 12,582,912
    ushort*   WhyT  = (ushort*)  (w + 46137344);       //  1,048,576
    float*    biasc = (float*)   (w + 47185920);       //     16,384
    float*    cst   = (float*)   (w + 47202304);       //    262,144
    uint32_t* flags = (uint32_t*)(w + 47464448);       //      4,096 (256 used)
    ushort*   hs    = (ushort*)  (w + 47468544);
    const size_t NEED_A = 47468544 + (size_t)(T_ + 1) * BH * 2;  // 114,708,480
    const size_t NEED_B = 47468544 + (size_t)65 * BH * 2;        //  55,988,224
    if (ws_size < NEED_B) return;
    const bool fullhs = (ws_size >= NEED_A);

    k_pack_x<<<2048, 256, 0, stream>>>(x, xP);
    k_build_wcT<<<4096, 256, 0, stream>>>(wxi, wxf, wxo, wxc, whi, whf, who, whc, WcT);
    k_build_whyT<<<512, 256, 0, stream>>>(why, WhyT);
    k_build_bias<<<16, 256, 0, stream>>>(bi, bf_, bo, bc, biasc);

    hipMemsetAsync(cst, 0, (size_t)BH * 4, stream);
    hipMemsetAsync(hs,  0, (size_t)BH * 2, stream);

    const int nchunk = fullhs ? 1 : 8;
    const int steps  = fullhs ? T_ : 64;
    for (int c = 0; c < nchunk; ++c) {
        const int t0 = c * steps;
        hipMemsetAsync(flags, 0, NWG * 4, stream);
        const ushort* a0 = WcT; const ushort* a1 = xP; ushort* a2 = hs;
        float* a3 = cst; const float* a4 = biasc; uint32_t* a5 = flags;
        int a6 = t0, a7 = steps;
        void* args[8] = {&a0, &a1, &a2, &a3, &a4, &a5, &a6, &a7};
        hipError_t e = hipLaunchCooperativeKernel((const void*)k_persist,
                                                  dim3(NWG), dim3(256), args, 0, stream);
        if (e != hipSuccess) {
            // fallback: plain launch; 256 single-WG/CU blocks (132KB LDS) are co-resident
            k_persist<<<dim3(NWG), dim3(256), 0, stream>>>(WcT, xP, hs, cst, biasc,
                                                           flags, t0, steps);
        }
        if (!fullhs) {
            k_yproj<<<dim3(64, O_ / 64), 64, 0, stream>>>(WhyT, hs, by, out, t0);
            if (c != nchunk - 1)
                hipMemcpyAsync(hs, hs + (size_t)64 * BH, (size_t)BH * 2,
                               hipMemcpyDeviceToDevice, stream);
        }
    }
    if (fullhs)
        k_yproj<<<dim3(T_, O_ / 64), 64, 0, stream>>>(WhyT, hs, by, out, 0);
}

// Round 8
// 2694.675 us; speedup vs baseline: 1.3700x; 1.2203x over previous
//
#include <hip/hip_runtime.h>
#include <hip/hip_bf16.h>
#include <cstdint>

// Problem constants
#define B_   64
#define T_   512
#define IN_  512
#define H_   1024
#define O_   512
#define NG   4096              // 4*H, gate-interleaved: n = 4h+g
#define KC   1536              // IN_ + H_
#define BT   32768             // B*T
#define BH   65536             // ushorts per h slot (B*H); 131072 bytes
#define NWG  256               // one WG per CU

#define GLB __attribute__((address_space(1)))
#define LDSAS __attribute__((address_space(3)))

using bs8 = __attribute__((ext_vector_type(8))) short;   // 8 x bf16
using f4  = __attribute__((ext_vector_type(4))) float;
using u32x4 = __attribute__((ext_vector_type(4))) unsigned int;

__device__ __forceinline__ ushort f2bf(float f) {
    union { float f; uint32_t u; } v; v.f = f;
    uint32_t r = v.u + 0x7fffu + ((v.u >> 16) & 1u);
    return (ushort)(r >> 16);
}
__device__ __forceinline__ float sigm(float x) { return 1.f / (1.f + __expf(-x)); }
__device__ __forceinline__ float tanh_(float x) {
    x = fminf(fmaxf(x, -15.f), 15.f);
    float e = __expf(2.f * x);
    return (e - 1.f) / (e + 1.f);
}

// ---------------- conversion / layout kernels ----------------

// xP[t][kk][b][32] (kk = k/32, 16 chunks of IN_), coalesced consumer reads
__global__ void k_pack_x(const float* __restrict__ x, ushort* __restrict__ xP) {
    const int n8 = BT * IN_ / 8;
    for (int i = blockIdx.x * blockDim.x + threadIdx.x; i < n8; i += gridDim.x * blockDim.x) {
        const int e8 = i & 3, b = (i >> 2) & 63, kk = (i >> 8) & 15, t = i >> 12;
        const float* s = x + ((size_t)b * T_ + t) * IN_ + kk * 32 + e8 * 8;
        f4 v0 = *reinterpret_cast<const f4*>(s);
        f4 v1 = *reinterpret_cast<const f4*>(s + 4);
        uint4 q;
        q.x = (uint32_t)f2bf(v0[0]) | ((uint32_t)f2bf(v0[1]) << 16);
        q.y = (uint32_t)f2bf(v0[2]) | ((uint32_t)f2bf(v0[3]) << 16);
        q.z = (uint32_t)f2bf(v1[0]) | ((uint32_t)f2bf(v1[1]) << 16);
        q.w = (uint32_t)f2bf(v1[2]) | ((uint32_t)f2bf(v1[3]) << 16);
        *reinterpret_cast<uint4*>(xP + ((size_t)t * 16 + kk) * 2048 + b * 32 + e8 * 8) = q;
    }
}

// WcT[n][k] (bf16), n = 4h+g; k<512 -> Wx_g[k][h], k>=512 -> Wh_g[k-512][h]
__global__ void k_build_wcT(const float* __restrict__ xi, const float* __restrict__ xf,
                            const float* __restrict__ xo, const float* __restrict__ xc,
                            const float* __restrict__ hi, const float* __restrict__ hf,
                            const float* __restrict__ ho, const float* __restrict__ hc,
                            ushort* __restrict__ dst) {
    const int total = NG * KC;
    for (int i = blockIdx.x * blockDim.x + threadIdx.x; i < total; i += gridDim.x * blockDim.x) {
        int n = i / KC, k = i - n * KC;
        int g = n & 3, h = n >> 2;
        float v;
        if (k < IN_) {
            const float* s = (g == 0) ? xi : ((g == 1) ? xf : ((g == 2) ? xo : xc));
            v = s[(size_t)k * H_ + h];
        } else {
            const float* s = (g == 0) ? hi : ((g == 1) ? hf : ((g == 2) ? ho : hc));
            v = s[(size_t)(k - IN_) * H_ + h];
        }
        dst[i] = f2bf(v);
    }
}

__global__ void k_build_whyT(const float* __restrict__ w, ushort* __restrict__ dst) {
    const int total = O_ * H_;
    for (int i = blockIdx.x * blockDim.x + threadIdx.x; i < total; i += gridDim.x * blockDim.x) {
        int o = i >> 10, k = i & (H_ - 1);
        dst[i] = f2bf(w[(size_t)k * O_ + o]);
    }
}

__global__ void k_build_bias(const float* __restrict__ bi, const float* __restrict__ bff,
                             const float* __restrict__ bo, const float* __restrict__ bc,
                             float* __restrict__ dst) {
    int i = blockIdx.x * blockDim.x + threadIdx.x;
    if (i < NG) {
        int g = i & 3, h = i >> 2;
        dst[i] = (g == 0) ? bi[h] : ((g == 1) ? bff[h] : ((g == 2) ? bo[h] : bc[h]));
    }
}

// ---------------- persistent LSTM ----------------
// h layout (quad-major): h[s][q=u>>2][b][u&3], 512 B per quad row -> WG g's output
// (q == g) is ONE contiguous 512 B store. Consumer wave w stages its 16-b slice of
// each of 32 k-chunks (1 KB each) via gll16 into PRIVATE LDS; counted-vmcnt pipeline.
__global__ void __launch_bounds__(256) __attribute__((amdgpu_waves_per_eu(1, 1)))
k_persist(const ushort* __restrict__ WcT, const ushort* __restrict__ xP,
          ushort* __restrict__ hs, float* __restrict__ cst,
          const float* __restrict__ biasc, uint32_t* __restrict__ flags,
          int t0, int nsteps) {
    __shared__ char Hst[4][32][1024];     // 128 KB: per-wave private staging
    __shared__ ushort hout[64][4];        // 512 B
    const int g = blockIdx.x, tid = threadIdx.x;
    const int lane = tid & 63, w = tid >> 6;
    const int n0 = g * 16;
    const int l15 = lane & 15, lq = lane >> 4;

    // W slice -> registers (full budget via waves_per_eu(1,1)): row n0+l15, k = c*32+lq*8
    bs8 wf[48];
#pragma unroll
    for (int c = 0; c < 48; ++c)
        wf[c] = *reinterpret_cast<const bs8*>(WcT + (size_t)(n0 + l15) * KC + c * 32 + lq * 8);

    // elementwise cell: b = w*16+l15, h-unit u = g*4+lq
    const int bmy = w * 16 + l15;
    const int u = g * 4 + lq;
    const f4 bia = *reinterpret_cast<const f4*>(biasc + n0 + lq * 4);
    float creg = (t0 == 0) ? 0.f : cst[(size_t)bmy * H_ + u];

    // staging addresses
    // global per-lane byte offset within a slot: quad q = c*8 + (lane>>3), 16B at b = w*16+(lane&7)*2
    const int lgo = ((lane >> 3) * 512) + (w * 128) + ((lane & 7) * 16);
    const char* hsb = (const char*)hs;
    // x prefetch base (layout [t][kk][b][32])
    const ushort* xb = xP + (size_t)bmy * 32 + lq * 8;
    // LDS read base for this lane within a staged chunk
    const int lro = ((l15 >> 1) * 16) + ((l15 & 1) * 8);

    // prefetch x chunks for step 0
    bs8 xv[16];
#pragma unroll
    for (int c = 0; c < 16; ++c)
        xv[c] = *reinterpret_cast<const bs8*>(xb + ((size_t)t0 * 16 + c) * 2048);

    __syncthreads();

    f4 acc[4];
    // consume one staged h chunk c: two 8B LDS pieces -> bs8 -> MFMA
    auto hcons = [&](int c) {
        const char* base = &Hst[w][c][0] + lro;
        union { bs8 v; uint2 p[2]; } uu;
        uu.p[0] = *reinterpret_cast<const uint2*>(base + (lq * 2 + 0) * 128);
        uu.p[1] = *reinterpret_cast<const uint2*>(base + (lq * 2 + 1) * 128);
        acc[c & 3] = __builtin_amdgcn_mfma_f32_16x16x32_bf16(wf[16 + c], uu.v, acc[c & 3], 0, 0, 0);
    };

    for (int s = 0; s < nsteps; ++s) {
        // 1) issue all 32 private gll16 for h_s (visible per previous poll)
        const char* slot = hsb + (size_t)s * 131072 + lgo;
#pragma unroll
        for (int c = 0; c < 32; ++c)
            __builtin_amdgcn_global_load_lds((const GLB uint32_t*)(slot + c * 4096),
                                             (LDSAS uint32_t*)(&Hst[w][c][0]), 16, 0, 0);

        // 2) x-MFMAs (reg operands) overlap the staging latency
#pragma unroll
        for (int c = 0; c < 4; ++c) acc[c] = (f4){0.f, 0.f, 0.f, 0.f};
#pragma unroll
        for (int c = 0; c < 16; ++c)
            acc[c & 3] = __builtin_amdgcn_mfma_f32_16x16x32_bf16(wf[c], xv[c], acc[c & 3], 0, 0, 0);

        // 3) counted-vmcnt h pipeline: 4 batches of 8 chunks
        asm volatile("s_waitcnt vmcnt(24)" ::: "memory");
        __builtin_amdgcn_sched_barrier(0);
#pragma unroll
        for (int j = 0; j < 8; ++j) hcons(j);
        asm volatile("s_waitcnt vmcnt(16)" ::: "memory");
        __builtin_amdgcn_sched_barrier(0);
#pragma unroll
        for (int j = 8; j < 16; ++j) hcons(j);
        asm volatile("s_waitcnt vmcnt(8)" ::: "memory");
        __builtin_amdgcn_sched_barrier(0);
#pragma unroll
        for (int j = 16; j < 24; ++j) hcons(j);
        asm volatile("s_waitcnt vmcnt(0)" ::: "memory");
        __builtin_amdgcn_sched_barrier(0);
#pragma unroll
        for (int j = 24; j < 32; ++j) hcons(j);

        f4 ssum = (acc[0] + acc[1]) + (acc[2] + acc[3]);

        // 4) elementwise; write h -> LDS repack
        {
            float pi = ssum[0] + bia[0], pf = ssum[1] + bia[1];
            float po = ssum[2] + bia[2], pc = ssum[3] + bia[3];
            float iv = sigm(pi), fv = sigm(pf), ov = sigm(po), cv = tanh_(pc);
            creg = fv * creg + iv * cv;
            hout[bmy][lq] = f2bf(ov * tanh_(creg));
        }
        __syncthreads();

        // 5) wave 0: ONE contiguous 512B coherent store (quad g); release flag
        if (w == 0) {
            uint2 hv2 = *reinterpret_cast<uint2*>(&hout[lane][0]);
            char* dst = (char*)hs + (size_t)(s + 1) * 131072 + (size_t)g * 512 + lane * 8;
            asm volatile("global_store_dwordx2 %0, %1, off sc0 sc1" :: "v"(dst), "v"(hv2) : "memory");
            asm volatile("s_waitcnt vmcnt(0)" ::: "memory");
            if (tid == 0)
                __hip_atomic_store(&flags[g], (uint32_t)(s + 1),
                                   __ATOMIC_RELAXED, __HIP_MEMORY_SCOPE_AGENT);
        }

        if (s + 1 < nsteps) {
            // prefetch next x during the wait window
#pragma unroll
            for (int c = 0; c < 16; ++c)
                xv[c] = *reinterpret_cast<const bs8*>(xb + ((size_t)(t0 + s + 1) * 16 + c) * 2048);
            // wave 0 polls all 256 flags: one coherent dwordx4 per lane
            if (w == 0) {
                const uint32_t tgt = (uint32_t)(s + 1);
                const uint32_t* fp = flags + lane * 4;
                for (;;) {
                    u32x4 f;
                    asm volatile("global_load_dwordx4 %0, %1, off sc0 sc1\n\t"
                                 "s_waitcnt vmcnt(0)"
                                 : "=v"(f) : "v"(fp) : "memory");
                    if (__all((int)(f.x >= tgt && f.y >= tgt && f.z >= tgt && f.w >= tgt))) break;
                    __builtin_amdgcn_s_sleep(1);
                }
            }
            __syncthreads();   // release all waves; h_{s+1} visible
        }
    }

    cst[(size_t)bmy * H_ + u] = creg;
}

// ---------------- output projection (quad-major h input) ----------------
__global__ void __launch_bounds__(64) k_yproj(const ushort* __restrict__ WhyT,
                                              const ushort* __restrict__ hsbase,
                                              const float* __restrict__ by,
                                              float* __restrict__ out, int t_off) {
    const int lane = threadIdx.x;
    const int tloc = blockIdx.x;
    const int o0 = blockIdx.y * 64;
    const int l15 = lane & 15, lq = lane >> 4, lk = lq * 8;
    const int t = t_off + tloc;

    const char* slot = (const char*)(hsbase + (size_t)(tloc + 1) * BH);
    const ushort* apm[4];
#pragma unroll
    for (int m = 0; m < 4; ++m) apm[m] = WhyT + (size_t)(o0 + m * 16 + l15) * H_ + lk;

    f4 acc[4][4] = {};
    for (int kk = 0; kk < 32; ++kk) {
        bs8 a[4], b[4];
#pragma unroll
        for (int m = 0; m < 4; ++m) a[m] = *reinterpret_cast<const bs8*>(apm[m] + kk * 32);
#pragma unroll
        for (int n = 0; n < 4; ++n) {
            const int bb = n * 16 + l15;
            union { bs8 v; uint2 p[2]; } uu;
            uu.p[0] = *reinterpret_cast<const uint2*>(slot + (size_t)(kk * 8 + lq * 2 + 0) * 512 + bb * 8);
            uu.p[1] = *reinterpret_cast<const uint2*>(slot + (size_t)(kk * 8 + lq * 2 + 1) * 512 + bb * 8);
            b[n] = uu.v;
        }
#pragma unroll
        for (int m = 0; m < 4; ++m)
#pragma unroll
            for (int n = 0; n < 4; ++n)
                acc[m][n] = __builtin_amdgcn_mfma_f32_16x16x32_bf16(a[m], b[n], acc[m][n], 0, 0, 0);
    }

#pragma unroll
    for (int m = 0; m < 4; ++m) {
        const int ob = o0 + m * 16 + lq * 4;
        const f4 bb = *reinterpret_cast<const f4*>(by + ob);
#pragma unroll
        for (int n = 0; n < 4; ++n) {
            const int b_ = n * 16 + l15;
            f4 v = acc[m][n] + bb;
            *reinterpret_cast<f4*>(out + ((size_t)b_ * T_ + t) * O_ + ob) = v;
        }
    }
}

// ---------------- launch ----------------

extern "C" void kernel_launch(void* const* d_in, const int* in_sizes, int n_in,
                              void* d_out, int out_size, void* d_ws, size_t ws_size,
                              hipStream_t stream) {
    const float* x   = (const float*)d_in[0];
    const float* wxi = (const float*)d_in[1];
    const float* whi = (const float*)d_in[2];
    const float* bi  = (const float*)d_in[3];
    const float* wxf = (const float*)d_in[4];
    const float* whf = (const float*)d_in[5];
    const float* bf_ = (const float*)d_in[6];
    const float* wxo = (const float*)d_in[7];
    const float* who = (const float*)d_in[8];
    const float* bo  = (const float*)d_in[9];
    const float* wxc = (const float*)d_in[10];
    const float* whc = (const float*)d_in[11];
    const float* bc  = (const float*)d_in[12];
    const float* why = (const float*)d_in[13];
    const float* by  = (const float*)d_in[14];
    float* out = (float*)d_out;

    uint8_t* w = (uint8_t*)d_ws;
    ushort*   xP    = (ushort*)  (w);                  // 33,554,432
    ushort*   WcT   = (ushort*)  (w + 33554432);       // 12,582,912
    ushort*   WhyT  = (ushort*)  (w + 46137344);       //  1,048,576
    float*    biasc = (float*)   (w + 47185920);       //     16,384
    float*    cst   = (float*)   (w + 47202304);       //    262,144
    uint32_t* flags = (uint32_t*)(w + 47464448);       //      4,096 (1024 used)
    ushort*   hs    = (ushort*)  (w + 47468544);
    const size_t NEED_A = 47468544 + (size_t)(T_ + 1) * BH * 2;  // 114,708,480
    const size_t NEED_B = 47468544 + (size_t)65 * BH * 2;        //  55,988,224
    if (ws_size < NEED_B) return;
    const bool fullhs = (ws_size >= NEED_A);

    k_pack_x<<<2048, 256, 0, stream>>>(x, xP);
    k_build_wcT<<<4096, 256, 0, stream>>>(wxi, wxf, wxo, wxc, whi, whf, who, whc, WcT);
    k_build_whyT<<<512, 256, 0, stream>>>(why, WhyT);
    k_build_bias<<<16, 256, 0, stream>>>(bi, bf_, bo, bc, biasc);

    hipMemsetAsync(cst, 0, (size_t)BH * 4, stream);
    hipMemsetAsync(hs,  0, (size_t)BH * 2, stream);

    const int nchunk = fullhs ? 1 : 8;
    const int steps  = fullhs ? T_ : 64;
    for (int c = 0; c < nchunk; ++c) {
        const int t0 = c * steps;
        hipMemsetAsync(flags, 0, NWG * 4, stream);
        const ushort* a0 = WcT; const ushort* a1 = xP; ushort* a2 = hs;
        float* a3 = cst; const float* a4 = biasc; uint32_t* a5 = flags;
        int a6 = t0, a7 = steps;
        void* args[8] = {&a0, &a1, &a2, &a3, &a4, &a5, &a6, &a7};
        hipError_t e = hipLaunchCooperativeKernel((const void*)k_persist,
                                                  dim3(NWG), dim3(256), args, 0, stream);
        if (e != hipSuccess) {
            // fallback: plain launch; 256 single-WG/CU blocks (128.5KB LDS) are co-resident
            k_persist<<<dim3(NWG), dim3(256), 0, stream>>>(WcT, xP, hs, cst, biasc,
                                                           flags, t0, steps);
        }
        if (!fullhs) {
            k_yproj<<<dim3(64, O_ / 64), 64, 0, stream>>>(WhyT, hs, by, out, t0);
            if (c != nchunk - 1)
                hipMemcpyAsync(hs, hs + (size_t)64 * BH, (size_t)BH * 2,
                               hipMemcpyDeviceToDevice, stream);
        }
    }
    if (fullhs)
        k_yproj<<<dim3(T_, O_ / 64), 64, 0, stream>>>(WhyT, hs, by, out, 0);
}